// Round 5
// baseline (6981.720 us; speedup 1.0000x reference)
//
#include <hip/hip_runtime.h>
#include <hip/hip_bf16.h>
#include <math.h>

#define B_ 64
#define S_ 512
#define I_ 256
#define H_ 1024
#define O_ 256

#define OUT_OFF (B_*O_)      // 16384 floats: final output
#define SLOT    (B_*H_)      // 65536 floats per hidden timestep slot

typedef __attribute__((ext_vector_type(8))) short bf16x8;  // 8 bf16 = 4 VGPRs
typedef __attribute__((ext_vector_type(4))) float f32x4;
typedef unsigned long long u64;

#define LDSK 1032            // padded row stride (1024+8 bf16): 2-way bank alias only (free)
#define NBLK 16              // persistent blocks (one 64-row W slice each)
#define ROWS 64              // h-rows per block

#define AGENT_LD(p)     __hip_atomic_load((p),  __ATOMIC_RELAXED, __HIP_MEMORY_SCOPE_AGENT)
#define AGENT_ST(p, v)  __hip_atomic_store((p), (v), __ATOMIC_RELAXED, __HIP_MEMORY_SCOPE_AGENT)

__device__ inline unsigned short bfb(float f) {
    return __builtin_bit_cast(unsigned short, __float2bfloat16(f));
}
__device__ inline bf16x8 cvt8(float4 a, float4 b) {
    bf16x8 r;
    r[0] = (short)bfb(a.x); r[1] = (short)bfb(a.y); r[2] = (short)bfb(a.z); r[3] = (short)bfb(a.w);
    r[4] = (short)bfb(b.x); r[5] = (short)bfb(b.y); r[6] = (short)bfb(b.z); r[7] = (short)bfb(b.w);
    return r;
}

// ---------------- zero hidden slot 0 + bf16 ping buffer 0 + flags ----------------
__global__ void k_zero(float* __restrict__ hid, float* __restrict__ hb0,
                       unsigned int* __restrict__ flg) {
    int i = blockIdx.x * 256 + threadIdx.x;          // 64 blocks * 256 = 16384 float4
    ((float4*)hid)[i] = make_float4(0.f, 0.f, 0.f, 0.f);
    if (i < B_ * H_ * 2 / 16)                        // 8192 float4 = 128 KB bf16 zeros
        ((float4*)hb0)[i] = make_float4(0.f, 0.f, 0.f, 0.f);
    if (i < 16)                                      // 64 flags (4 wave-groups x 16 slices)
        ((uint4*)flg)[i] = make_uint4(0u, 0u, 0u, 0u);
}

// ---------------- generic fp32 -> bf16 convert (count = grid*1024 elems) ----------------
__global__ void k_cvt(const float* __restrict__ src, unsigned short* __restrict__ dst) {
    int i = blockIdx.x * 256 + threadIdx.x;
    float4 v = ((const float4*)src)[i];
    ushort4 o;
    o.x = bfb(v.x); o.y = bfb(v.y); o.z = bfb(v.z); o.w = bfb(v.w);
    ((ushort4*)dst)[i] = o;
}

// ---------------- generic transpose src[R][C] -> dst[C][R] ----------------
__global__ void k_transpose(const float* __restrict__ src, float* __restrict__ dst,
                            int R, int C) {
    __shared__ float tile[32][33];
    int c0 = blockIdx.x * 32, r0 = blockIdx.y * 32;
    int tx = threadIdx.x, ty = threadIdx.y;          // block (32,8)
#pragma unroll
    for (int j = 0; j < 32; j += 8)
        tile[ty + j][tx] = src[(size_t)(r0 + ty + j) * C + c0 + tx];
    __syncthreads();
#pragma unroll
    for (int j = 0; j < 32; j += 8)
        dst[(size_t)(c0 + ty + j) * R + r0 + tx] = tile[tx][ty + j];
}

// ---------------- x_proj via MFMA (verified R4): hid[t+1][b][h] = bias + x.Wih ----------------
__global__ __launch_bounds__(256) void k_xproj(const unsigned short* __restrict__ xbf,   // [B][S][I]
                                               const unsigned short* __restrict__ wihbf, // [H][I]
                                               const float* __restrict__ bias,
                                               float* __restrict__ hid) {
    const int t    = blockIdx.x;
    const int lane = threadIdx.x & 63;
    const int w    = threadIdx.x >> 6;
    const int n    = lane & 15;
    const int quad = lane >> 4;

    bf16x8 afr[4][8];
#pragma unroll
    for (int bt = 0; bt < 4; ++bt) {
        const unsigned short* xp_ = xbf + ((size_t)(bt * 16 + n) * S_ + t) * I_ + quad * 8;
#pragma unroll
        for (int kk = 0; kk < 8; ++kk)
            afr[bt][kk] = *(const bf16x8*)(xp_ + kk * 32);
    }

    float* slot1 = hid + (size_t)(t + 1) * SLOT;
#pragma unroll 1
    for (int ht = 0; ht < 16; ++ht) {
        const int h0 = w * 256 + ht * 16;
        const unsigned short* wp = wihbf + (size_t)(h0 + n) * I_ + quad * 8;
        bf16x8 bfr[8];
#pragma unroll
        for (int kk = 0; kk < 8; ++kk) bfr[kk] = *(const bf16x8*)(wp + kk * 32);
        float bv = bias[h0 + n];
#pragma unroll
        for (int bt = 0; bt < 4; ++bt) {
            f32x4 acc = {0.f, 0.f, 0.f, 0.f};
#pragma unroll
            for (int kk = 0; kk < 8; ++kk)
                acc = __builtin_amdgcn_mfma_f32_16x16x32_bf16(afr[bt][kk], bfr[kk], acc, 0, 0, 0);
            const int b0 = bt * 16 + quad * 4;
#pragma unroll
            for (int r = 0; r < 4; ++r)
                slot1[(size_t)(b0 + r) * H_ + h0 + n] = acc[r] + bv;
        }
    }
}

// ---------------- fp32 fallback x_proj (small workspace) ----------------
__global__ __launch_bounds__(256) void k_xproj_f32(const float* __restrict__ x,
                                                   const float* __restrict__ wihT,
                                                   const float* __restrict__ bias,
                                                   float* __restrict__ hid) {
    const int t   = blockIdx.x;
    const int hq0 = blockIdx.y * 16;
    __shared__ float xs[B_][260];
    const int tid = threadIdx.x;
#pragma unroll
    for (int it = 0; it < 16; ++it) {
        int f4 = it * 256 + tid;
        int b = f4 >> 6, iq = f4 & 63;
        float4 v = ((const float4*)x)[(size_t)b * (S_ * I_ / 4) + t * (I_ / 4) + iq];
        *(float4*)&xs[b][iq * 4] = v;
    }
    __syncthreads();
    const int hq = tid & 15;
    const int b0 = (tid >> 4) * 4;
    float4 acc[4];
    float4 bs = ((const float4*)bias)[hq0 + hq];
#pragma unroll
    for (int i = 0; i < 4; ++i) acc[i] = bs;
    const float4* w4p = (const float4*)wihT;
#pragma unroll 4
    for (int k = 0; k < I_; ++k) {
        float4 w = w4p[(size_t)k * (H_ / 4) + hq0 + hq];
#pragma unroll
        for (int i = 0; i < 4; ++i) {
            float xv = xs[b0 + i][k];
            acc[i].x += xv * w.x; acc[i].y += xv * w.y;
            acc[i].z += xv * w.z; acc[i].w += xv * w.w;
        }
    }
    float4* out4 = (float4*)hid;
#pragma unroll
    for (int i = 0; i < 4; ++i)
        out4[(size_t)(t + 1) * (SLOT / 4) + (b0 + i) * (H_ / 4) + hq0 + hq] = acc[i];
}

// ---------------- persistent recurrence: 16 blocks, hot-line critical path ----------------
// Block owns 64 W-rows in LDS; per step each wave computes 4 row-tiles for its b-group.
// Critical path: bf16 store (hot L3 ping-pong) -> vmcnt(0) -> flag. fp32 hidden-state
// store issued AFTER the flag (lazy; collected by next step's drain). Poll = 1 line.
__global__ __launch_bounds__(256) void k_rnn(
    const unsigned short* __restrict__ whhbf,   // [H_][H_] bf16
    unsigned short* __restrict__ hb0,           // ping [B_][H_] bf16
    unsigned short* __restrict__ hb1,           // pong
    float* __restrict__ hid,
    const float* __restrict__ fcwT,             // [H_][O_]
    const float* __restrict__ fcb,
    float* __restrict__ outp,
    unsigned int* __restrict__ flg)             // [4][16] wave-group x slice
{
    const int slice = blockIdx.x;
    const int tid   = threadIdx.x;
    __shared__ unsigned short Ws[ROWS * LDSK];  // 129 KB padded -> 132 KB
    __shared__ float hl[H_];                    // 4 KB (fused fc)

    {   // stage 64 W rows (128 KB contiguous) -> padded LDS, once
        const float4* src = (const float4*)(whhbf + (size_t)slice * ROWS * H_);
#pragma unroll
        for (int it = 0; it < 32; ++it) {
            int c = it * 256 + tid;              // 8192 chunks of 16B
            float4 v = src[c];
            int row = c >> 7, off = (c & 127) * 8;
            *(float4*)&Ws[row * LDSK + off] = v;
        }
    }
    __syncthreads();

    const int w    = tid >> 6;                   // wave = b-group (independent pipeline)
    const int lane = tid & 63;
    const int n    = lane & 15;
    const int quad = lane >> 4;
    const int b    = w * 16 + n;
    const int r0b  = slice * ROWS + quad * 4;    // D: row = quad*4+reg (+rt*16), col = n

    const unsigned short* ap = &Ws[n * LDSK + quad * 8];
    const size_t boff = (size_t)b * H_ + quad * 8;
    const u64* rb[2] = {(const u64*)(hb0 + boff), (const u64*)(hb1 + boff)};
    unsigned int* myflag = &flg[w * 16 + slice];
    const unsigned int* pollp = &flg[w * 16 + (lane & 15)];  // one 64B line per wave-group

    for (int t = 0; t < S_; ++t) {
        float* slot1 = hid + (size_t)(t + 1) * SLOT;
        // xp prefetch (no flag dependency): 4 tiles x 16B, latency hides under poll+MFMA
        u64* xpp[4]; u64 xl[4], xh[4];
#pragma unroll
        for (int rt = 0; rt < 4; ++rt) {
            xpp[rt] = (u64*)(slot1 + (size_t)b * H_ + r0b + rt * 16);
            xl[rt] = AGENT_LD(xpp[rt]);
            xh[rt] = AGENT_LD(xpp[rt] + 1);
        }

        if (t) {   // wait for all 16 same-w slices to have published step t
            unsigned f = AGENT_LD(pollp);
            while (!__all(f >= (unsigned)t)) {
                __builtin_amdgcn_s_sleep(1);
                f = AGENT_LD(pollp);
            }
            asm volatile("" ::: "memory");       // data loads stay below the poll
        }

        const u64* bq = rb[t & 1];
        f32x4 acc[4] = {{0.f,0.f,0.f,0.f},{0.f,0.f,0.f,0.f},{0.f,0.f,0.f,0.f},{0.f,0.f,0.f,0.f}};
#pragma unroll 8
        for (int kk = 0; kk < 32; ++kk) {
            union { u64 u[2]; bf16x8 v; } bc;
            bc.u[0] = AGENT_LD(bq + kk * 8);
            bc.u[1] = AGENT_LD(bq + kk * 8 + 1);
#pragma unroll
            for (int rt = 0; rt < 4; ++rt) {
                bf16x8 a = *(const bf16x8*)(ap + (size_t)rt * 16 * LDSK + kk * 32);
                acc[rt] = __builtin_amdgcn_mfma_f32_16x16x32_bf16(a, bc.v, acc[rt], 0, 0, 0);
            }
        }

        float hv[4][4];
        u64 d0[4], d1[4];
#pragma unroll
        for (int rt = 0; rt < 4; ++rt) {
            float x0 = __builtin_bit_cast(float, (unsigned)(xl[rt] & 0xffffffffu));
            float x1 = __builtin_bit_cast(float, (unsigned)(xl[rt] >> 32));
            float x2 = __builtin_bit_cast(float, (unsigned)(xh[rt] & 0xffffffffu));
            float x3 = __builtin_bit_cast(float, (unsigned)(xh[rt] >> 32));
            hv[rt][0] = tanhf(acc[rt][0] + x0);
            hv[rt][1] = tanhf(acc[rt][1] + x1);
            hv[rt][2] = tanhf(acc[rt][2] + x2);
            hv[rt][3] = tanhf(acc[rt][3] + x3);
            d0[rt] = (u64)__builtin_bit_cast(unsigned, hv[rt][0]) |
                     ((u64)__builtin_bit_cast(unsigned, hv[rt][1]) << 32);
            d1[rt] = (u64)__builtin_bit_cast(unsigned, hv[rt][2]) |
                     ((u64)__builtin_bit_cast(unsigned, hv[rt][3]) << 32);
        }

        const bool last = (t == S_ - 1);
        if (!last) {
            unsigned short* hbn = (t & 1) ? hb0 : hb1;   // write hb[(t+1)&1] (hot lines)
#pragma unroll
            for (int rt = 0; rt < 4; ++rt) {
                u64 pk = (u64)bfb(hv[rt][0]) | ((u64)bfb(hv[rt][1]) << 16) |
                         ((u64)bfb(hv[rt][2]) << 32) | ((u64)bfb(hv[rt][3]) << 48);
                AGENT_ST((u64*)(hbn + (size_t)b * H_ + r0b + rt * 16), pk);
            }
        } else {
#pragma unroll
            for (int rt = 0; rt < 4; ++rt) {             // slot S_ must be drained pre-flag
                AGENT_ST(xpp[rt], d0[rt]);
                AGENT_ST(xpp[rt] + 1, d1[rt]);
            }
        }

        // drain only hot-path stores (+ previous step's lazy fp32), then publish
        asm volatile("s_waitcnt vmcnt(0)" ::: "memory");
        if (lane == 0) AGENT_ST(myflag, (unsigned)(t + 1));

        if (!last) {   // lazy fp32 hidden-state store: cold lines, off the critical path
#pragma unroll
            for (int rt = 0; rt < 4; ++rt) {
                AGENT_ST(xpp[rt], d0[rt]);
                AGENT_ST(xpp[rt] + 1, d1[rt]);
            }
        }
    }

    // ---- fused final fc: block handles batches slice*4 .. slice*4+3
    {
        const unsigned int* fp2 = &flg[lane];    // all 64 (w,slice) flags
        unsigned f = AGENT_LD(fp2);
        while (!__all(f >= (unsigned)S_)) {
            __builtin_amdgcn_s_sleep(1);
            f = AGENT_LD(fp2);
        }
        asm volatile("" ::: "memory");
        __syncthreads();

#pragma unroll 1
        for (int j = 0; j < 4; ++j) {
            const int bb = slice * 4 + j;
            const u64* hsrc = (const u64*)(hid + (size_t)S_ * SLOT + (size_t)bb * H_);
            u64 a0 = AGENT_LD(hsrc + tid * 2);
            u64 a1 = AGENT_LD(hsrc + tid * 2 + 1);
            hl[tid * 4 + 0] = __builtin_bit_cast(float, (unsigned)(a0 & 0xffffffffu));
            hl[tid * 4 + 1] = __builtin_bit_cast(float, (unsigned)(a0 >> 32));
            hl[tid * 4 + 2] = __builtin_bit_cast(float, (unsigned)(a1 & 0xffffffffu));
            hl[tid * 4 + 3] = __builtin_bit_cast(float, (unsigned)(a1 >> 32));
            __syncthreads();
            float acc = fcb[tid];
#pragma unroll 4
            for (int k = 0; k < H_; ++k)
                acc += fcwT[(size_t)k * O_ + tid] * hl[k];
            outp[bb * O_ + tid] = acc;
            __syncthreads();
        }
    }
}

// ---------------- fallback per-step kernel (plain loads; kernel-boundary coherence) ----------------
#define LDSK64 1032
__global__ __launch_bounds__(256) void k_step2(const unsigned short* __restrict__ whhbf,
                                               float* __restrict__ hid, int t) {
    const int slice = blockIdx.x;
    __shared__ unsigned short Wsf[16 * LDSK64];
    const int tid = threadIdx.x;
    {
        const float4* src = (const float4*)(whhbf + (size_t)slice * 16 * H_);
#pragma unroll
        for (int it = 0; it < 8; ++it) {
            int c = it * 256 + tid;
            float4 v = src[c];
            int row = c >> 7, off = (c & 127) * 8;
            *(float4*)&Wsf[row * LDSK64 + off] = v;
        }
    }
    __syncthreads();

    const int w = tid >> 6, lane = tid & 63;
    const int n = lane & 15, quad = lane >> 4;
    const int b = w * 16 + n;
    const int r0 = slice * 16 + quad * 4;
    const unsigned short* ap = &Wsf[n * LDSK64 + quad * 8];
    const float* hsrc = hid + (size_t)t * SLOT + (size_t)b * H_ + quad * 8;

    f32x4 acc0 = {0.f, 0.f, 0.f, 0.f};
    f32x4 acc1 = {0.f, 0.f, 0.f, 0.f};
#pragma unroll 8
    for (int kk = 0; kk < 32; kk += 2) {
        float4 p0 = *(const float4*)(hsrc + kk * 32);
        float4 p1 = *(const float4*)(hsrc + kk * 32 + 4);
        float4 q0 = *(const float4*)(hsrc + (kk + 1) * 32);
        float4 q1 = *(const float4*)(hsrc + (kk + 1) * 32 + 4);
        bf16x8 a0 = *(const bf16x8*)(ap + kk * 32);
        bf16x8 a1 = *(const bf16x8*)(ap + (kk + 1) * 32);
        acc0 = __builtin_amdgcn_mfma_f32_16x16x32_bf16(a0, cvt8(p0, p1), acc0, 0, 0, 0);
        acc1 = __builtin_amdgcn_mfma_f32_16x16x32_bf16(a1, cvt8(q0, q1), acc1, 0, 0, 0);
    }
    float4* slot1 = (float4*)(hid + (size_t)(t + 1) * SLOT);
    size_t idx = (size_t)b * (H_ / 4) + (r0 >> 2);
    float4 xp = slot1[idx];
    float4 hv;
    hv.x = tanhf(acc0[0] + acc1[0] + xp.x);
    hv.y = tanhf(acc0[1] + acc1[1] + xp.y);
    hv.z = tanhf(acc0[2] + acc1[2] + xp.z);
    hv.w = tanhf(acc0[3] + acc1[3] + xp.w);
    slot1[idx] = hv;
}

__global__ __launch_bounds__(256) void k_fc(const float* __restrict__ fcwT,
                                            const float* __restrict__ fcb,
                                            const float* __restrict__ hid,
                                            float* __restrict__ outp) {
    const int b = blockIdx.x;
    __shared__ float hl[H_];
    const int tid = threadIdx.x;
    ((float4*)hl)[tid] = ((const float4*)(hid + (size_t)S_ * SLOT + b * H_))[tid];
    __syncthreads();
    float acc = fcb[tid];
#pragma unroll 4
    for (int k = 0; k < H_; ++k)
        acc += fcwT[(size_t)k * O_ + tid] * hl[k];
    outp[b * O_ + tid] = acc;
}

extern "C" void kernel_launch(void* const* d_in, const int* in_sizes, int n_in,
                              void* d_out, int out_size, void* d_ws, size_t ws_size,
                              hipStream_t stream) {
    const float* x    = (const float*)d_in[0];
    const float* wih  = (const float*)d_in[1];
    const float* whh  = (const float*)d_in[2];
    const float* bias = (const float*)d_in[3];
    const float* fcw  = (const float*)d_in[4];
    const float* fcb  = (const float*)d_in[5];

    float* outp = (float*)d_out;
    float* hid  = outp + OUT_OFF;

    // big:   whhbf 2MB | xbf 16.8MB | wihbf 0.5MB | fcwT 1MB | hb0 128K | hb1 128K | flg
    // small: whhbf 2MB | wihT 1MB | fcwT 1MB | hb0 | hb1 | flg
    unsigned short* whhbf = (unsigned short*)d_ws;
    const size_t need_big = (size_t)H_ * H_ * 2 + (size_t)B_ * S_ * I_ * 2 +
                            (size_t)H_ * I_ * 2 + (size_t)H_ * O_ * 4 +
                            (size_t)B_ * H_ * 4 + 1024;
    const bool big = ws_size >= need_big;

    unsigned short* xbf   = whhbf + (size_t)H_ * H_;
    unsigned short* wihbf = xbf + (size_t)B_ * S_ * I_;
    float* fcwT_big = (float*)(wihbf + (size_t)H_ * I_);
    unsigned short* hb0_big = (unsigned short*)(fcwT_big + (size_t)H_ * O_);

    float* wihT = (float*)(whhbf + (size_t)H_ * H_);
    float* fcwT_sm = wihT + (size_t)I_ * H_;
    unsigned short* hb0_sm = (unsigned short*)(fcwT_sm + (size_t)H_ * O_);

    float* fcwT = big ? fcwT_big : fcwT_sm;
    unsigned short* hb0 = big ? hb0_big : hb0_sm;
    unsigned short* hb1 = hb0 + (size_t)B_ * H_;
    unsigned int* flg = (unsigned int*)(hb1 + (size_t)B_ * H_);

    k_zero<<<SLOT / 4 / 256, 256, 0, stream>>>(hid, (float*)hb0, flg);
    k_cvt<<<H_ * H_ / 1024, 256, 0, stream>>>(whh, whhbf);
    k_transpose<<<dim3(H_ / 32, O_ / 32), dim3(32, 8), 0, stream>>>(fcw, fcwT, O_, H_);

    if (big) {
        k_cvt<<<B_ * S_ * I_ / 1024, 256, 0, stream>>>(x, xbf);
        k_cvt<<<H_ * I_ / 1024, 256, 0, stream>>>(wih, wihbf);
        k_xproj<<<S_, 256, 0, stream>>>(xbf, wihbf, bias, hid);
    } else {
        k_transpose<<<dim3(I_ / 32, H_ / 32), dim3(32, 8), 0, stream>>>(wih, wihT, H_, I_);
        k_xproj_f32<<<dim3(S_, H_ / 64), 256, 0, stream>>>(x, wihT, bias, hid);
    }

    void* args[] = {(void*)&whhbf, (void*)&hb0, (void*)&hb1, (void*)&hid,
                    (void*)&fcwT, (void*)&fcb, (void*)&outp, (void*)&flg};
    hipError_t e = hipLaunchCooperativeKernel((const void*)k_rnn, dim3(NBLK), dim3(256),
                                              args, 0, stream);
    if (e != hipSuccess) {
        for (int t = 0; t < S_; ++t)
            k_step2<<<64, 256, 0, stream>>>(whhbf, hid, t);
        k_fc<<<B_, 256, 0, stream>>>(fcwT, fcb, hid, outp);
    }
}

// Round 12
// 3602.810 us; speedup vs baseline: 1.9379x; 1.9379x over previous
//
#include <hip/hip_runtime.h>
#include <hip/hip_bf16.h>
#include <math.h>

#define B_ 64
#define S_ 512
#define I_ 256
#define H_ 1024
#define O_ 256

#define OUT_OFF (B_*O_)      // 16384 floats: final output
#define SLOT    (B_*H_)      // 65536 floats per hidden timestep slot

typedef __attribute__((ext_vector_type(8))) short bf16x8;  // 8 bf16 = 4 VGPRs
typedef __attribute__((ext_vector_type(4))) float f32x4;

#define LDSK 1032            // padded row stride (1024 + 8 bf16): 2-way bank alias only (free)

__device__ inline unsigned short bfb(float f) {
    return __builtin_bit_cast(unsigned short, __float2bfloat16(f));
}

// ---------------- zero hidden slot 0 (h0 = 0) + hbf0 ----------------
__global__ void k_zero(float* __restrict__ hid, float* __restrict__ hbf0) {
    int i = blockIdx.x * 256 + threadIdx.x;          // 64 blocks * 256 = 16384 float4
    ((float4*)hid)[i] = make_float4(0.f, 0.f, 0.f, 0.f);
    if (i < B_ * H_ * 2 / 16)                        // 8192 float4 = 128 KB bf16 zeros
        ((float4*)hbf0)[i] = make_float4(0.f, 0.f, 0.f, 0.f);
}

// ---------------- generic fp32 -> bf16 convert (count = grid*1024 elems) ----------------
__global__ void k_cvt(const float* __restrict__ src, unsigned short* __restrict__ dst) {
    int i = blockIdx.x * 256 + threadIdx.x;
    float4 v = ((const float4*)src)[i];
    ushort4 o;
    o.x = bfb(v.x); o.y = bfb(v.y); o.z = bfb(v.z); o.w = bfb(v.w);
    ((ushort4*)dst)[i] = o;
}

// ---------------- generic transpose src[R][C] -> dst[C][R] ----------------
__global__ void k_transpose(const float* __restrict__ src, float* __restrict__ dst,
                            int R, int C) {
    __shared__ float tile[32][33];
    int c0 = blockIdx.x * 32, r0 = blockIdx.y * 32;
    int tx = threadIdx.x, ty = threadIdx.y;          // block (32,8)
#pragma unroll
    for (int j = 0; j < 32; j += 8)
        tile[ty + j][tx] = src[(size_t)(r0 + ty + j) * C + c0 + tx];
    __syncthreads();
#pragma unroll
    for (int j = 0; j < 32; j += 8)
        dst[(size_t)(c0 + ty + j) * R + r0 + tx] = tile[tx][ty + j];
}

// ---------------- x_proj via MFMA (verified R4/R5): hid[t+1][b][h] = bias + x.Wih ----------------
__global__ __launch_bounds__(256) void k_xproj(const unsigned short* __restrict__ xbf,   // [B][S][I]
                                               const unsigned short* __restrict__ wihbf, // [H][I]
                                               const float* __restrict__ bias,
                                               float* __restrict__ hid) {
    const int t    = blockIdx.x;
    const int lane = threadIdx.x & 63;
    const int w    = threadIdx.x >> 6;
    const int n    = lane & 15;
    const int quad = lane >> 4;

    bf16x8 afr[4][8];
#pragma unroll
    for (int bt = 0; bt < 4; ++bt) {
        const unsigned short* xp_ = xbf + ((size_t)(bt * 16 + n) * S_ + t) * I_ + quad * 8;
#pragma unroll
        for (int kk = 0; kk < 8; ++kk)
            afr[bt][kk] = *(const bf16x8*)(xp_ + kk * 32);
    }

    float* slot1 = hid + (size_t)(t + 1) * SLOT;
#pragma unroll 1
    for (int ht = 0; ht < 16; ++ht) {
        const int h0 = w * 256 + ht * 16;
        const unsigned short* wp = wihbf + (size_t)(h0 + n) * I_ + quad * 8;
        bf16x8 bfr[8];
#pragma unroll
        for (int kk = 0; kk < 8; ++kk) bfr[kk] = *(const bf16x8*)(wp + kk * 32);
        float bv = bias[h0 + n];
#pragma unroll
        for (int bt = 0; bt < 4; ++bt) {
            f32x4 acc = {0.f, 0.f, 0.f, 0.f};
#pragma unroll
            for (int kk = 0; kk < 8; ++kk)
                acc = __builtin_amdgcn_mfma_f32_16x16x32_bf16(afr[bt][kk], bfr[kk], acc, 0, 0, 0);
            const int b0 = bt * 16 + quad * 4;
#pragma unroll
            for (int r = 0; r < 4; ++r)
                slot1[(size_t)(b0 + r) * H_ + h0 + n] = acc[r] + bv;
        }
    }
}

// ---------------- fp32 fallback x_proj (small workspace; baseline-verified) ----------------
__global__ __launch_bounds__(256) void k_xproj_f32(const float* __restrict__ x,
                                                   const float* __restrict__ wihT, // [I_][H_]
                                                   const float* __restrict__ bias,
                                                   float* __restrict__ hid) {
    const int t   = blockIdx.x;
    const int hq0 = blockIdx.y * 16;
    __shared__ float xs[B_][260];
    const int tid = threadIdx.x;
#pragma unroll
    for (int it = 0; it < 16; ++it) {
        int f4 = it * 256 + tid;
        int b = f4 >> 6, iq = f4 & 63;
        float4 v = ((const float4*)x)[(size_t)b * (S_ * I_ / 4) + t * (I_ / 4) + iq];
        *(float4*)&xs[b][iq * 4] = v;
    }
    __syncthreads();
    const int hq = tid & 15;
    const int b0 = (tid >> 4) * 4;
    float4 acc[4];
    float4 bs = ((const float4*)bias)[hq0 + hq];
#pragma unroll
    for (int i = 0; i < 4; ++i) acc[i] = bs;
    const float4* w4p = (const float4*)wihT;
#pragma unroll 4
    for (int k = 0; k < I_; ++k) {
        float4 w = w4p[(size_t)k * (H_ / 4) + hq0 + hq];
#pragma unroll
        for (int i = 0; i < 4; ++i) {
            float xv = xs[b0 + i][k];
            acc[i].x += xv * w.x; acc[i].y += xv * w.y;
            acc[i].z += xv * w.z; acc[i].w += xv * w.w;
        }
    }
    float4* out4 = (float4*)hid;
#pragma unroll
    for (int i = 0; i < 4; ++i)
        out4[(size_t)(t + 1) * (SLOT / 4) + (b0 + i) * (H_ / 4) + hq0 + hq] = acc[i];
}

// ---------------- one recurrence step (baseline-verified + 2-chain acc from R1) ----------------
// D[16r x 16b] = W_rows[16 x 1024] * hT[1024 x 16b]; A = whhbf rows (LDS), B = hprev (global).
// grid 64 (slice = 16 r-rows), 256 thr = 4 waves, wave w = b-tile.
__global__ __launch_bounds__(256) void k_step(
    const unsigned short* __restrict__ whhbf,   // [H_][H_] bf16 natural
    const unsigned short* __restrict__ hprev,   // [B_][H_] bf16
    unsigned short* __restrict__ hnext,         // [B_][H_] bf16
    float* __restrict__ hid, int t)
{
    const int slice = blockIdx.x;
    __shared__ unsigned short Ws[16 * LDSK];
    const int tid = threadIdx.x;

    // stage 16 W rows (contiguous 32 KB) -> padded LDS
    {
        const float4* src = (const float4*)(whhbf + (size_t)slice * 16 * H_);
#pragma unroll
        for (int it = 0; it < 8; ++it) {
            int c = it * 256 + tid;                  // 2048 chunks of 16B (8 bf16)
            float4 v = src[c];
            int row = c >> 7, off = (c & 127) * 8;
            *(float4*)&Ws[row * LDSK + off] = v;
        }
    }
    __syncthreads();

    const int w    = tid >> 6;                       // wave = b-tile
    const int lane = tid & 63;
    const int n    = lane & 15;                      // A-row (r_local) AND B-col (b_local)
    const int quad = lane >> 4;

    const int b = w * 16 + n;
    f32x4 acc0 = {0.f, 0.f, 0.f, 0.f};
    f32x4 acc1 = {0.f, 0.f, 0.f, 0.f};               // 2 chains: halve dependent MFMA latency

    const unsigned short* ap = &Ws[n * LDSK + quad * 8];
    const unsigned short* bp = hprev + (size_t)b * H_ + quad * 8;

#pragma unroll
    for (int kk = 0; kk < 32; kk += 2) {
        bf16x8 a0 = *(const bf16x8*)(ap + kk * 32);
        bf16x8 v0 = *(const bf16x8*)(bp + kk * 32);
        acc0 = __builtin_amdgcn_mfma_f32_16x16x32_bf16(a0, v0, acc0, 0, 0, 0);
        bf16x8 a1 = *(const bf16x8*)(ap + (kk + 1) * 32);
        bf16x8 v1 = *(const bf16x8*)(bp + (kk + 1) * 32);
        acc1 = __builtin_amdgcn_mfma_f32_16x16x32_bf16(a1, v1, acc1, 0, 0, 0);
    }

    // C/D: row(M=r_local) = quad*4 + reg, col(N=b_local) = lane&15
    const int r0 = slice * 16 + quad * 4;
    float4* slot1 = (float4*)(hid + (size_t)(t + 1) * SLOT);
    size_t idx = (size_t)b * (H_ / 4) + (r0 >> 2);
    float4 xp = slot1[idx];                          // x_proj + bias (precomputed)
    float4 hv;
    hv.x = tanhf(acc0[0] + acc1[0] + xp.x);
    hv.y = tanhf(acc0[1] + acc1[1] + xp.y);
    hv.z = tanhf(acc0[2] + acc1[2] + xp.z);
    hv.w = tanhf(acc0[3] + acc1[3] + xp.w);
    slot1[idx] = hv;

    ushort4 hb;
    hb.x = bfb(hv.x);
    hb.y = bfb(hv.y);
    hb.z = bfb(hv.z);
    hb.w = bfb(hv.w);
    *(ushort4*)(hnext + (size_t)b * H_ + r0) = hb;
}

// ---------------- final fc (baseline-verified) ----------------
__global__ __launch_bounds__(256) void k_fc(const float* __restrict__ fcwT,  // [H_][O_]
                                            const float* __restrict__ fcb,
                                            const float* __restrict__ hid,
                                            float* __restrict__ outp) {
    const int b = blockIdx.x;
    __shared__ float hl[H_];
    const int tid = threadIdx.x;
    ((float4*)hl)[tid] = ((const float4*)(hid + (size_t)S_ * SLOT + b * H_))[tid];
    __syncthreads();
    float acc = fcb[tid];
#pragma unroll 4
    for (int k = 0; k < H_; ++k)
        acc += fcwT[(size_t)k * O_ + tid] * hl[k];
    outp[b * O_ + tid] = acc;
}

extern "C" void kernel_launch(void* const* d_in, const int* in_sizes, int n_in,
                              void* d_out, int out_size, void* d_ws, size_t ws_size,
                              hipStream_t stream) {
    const float* x    = (const float*)d_in[0];
    const float* wih  = (const float*)d_in[1];
    const float* whh  = (const float*)d_in[2];
    const float* bias = (const float*)d_in[3];
    const float* fcw  = (const float*)d_in[4];
    const float* fcb  = (const float*)d_in[5];

    float* outp = (float*)d_out;
    float* hid  = outp + OUT_OFF;

    // big:   whhbf 2M | xbf 16.8M | wihbf 0.5M | fcwT 1M | hbf0 128K | hbf1 128K
    // small: whhbf 2M | wihT 1M | fcwT 1M | hbf0 128K | hbf1 128K   (~4.3MB)
    unsigned short* whhbf = (unsigned short*)d_ws;
    const size_t need_big = (size_t)H_ * H_ * 2 + (size_t)B_ * S_ * I_ * 2 +
                            (size_t)H_ * I_ * 2 + (size_t)H_ * O_ * 4 +
                            (size_t)B_ * H_ * 4 + 1024;
    const bool big = ws_size >= need_big;

    unsigned short* xbf   = whhbf + (size_t)H_ * H_;
    unsigned short* wihbf = xbf + (size_t)B_ * S_ * I_;
    float* fcwT_big = (float*)(wihbf + (size_t)H_ * I_);
    unsigned short* hb0_big = (unsigned short*)(fcwT_big + (size_t)H_ * O_);

    float* wihT = (float*)(whhbf + (size_t)H_ * H_);
    float* fcwT_sm = wihT + (size_t)I_ * H_;
    unsigned short* hb0_sm = (unsigned short*)(fcwT_sm + (size_t)H_ * O_);

    float* fcwT = big ? fcwT_big : fcwT_sm;
    unsigned short* hbf0 = big ? hb0_big : hb0_sm;
    unsigned short* hbf1 = hbf0 + (size_t)B_ * H_;

    k_zero<<<SLOT / 4 / 256, 256, 0, stream>>>(hid, (float*)hbf0);
    k_cvt<<<H_ * H_ / 1024, 256, 0, stream>>>(whh, whhbf);
    k_transpose<<<dim3(H_ / 32, O_ / 32), dim3(32, 8), 0, stream>>>(fcw, fcwT, O_, H_);

    if (big) {
        k_cvt<<<B_ * S_ * I_ / 1024, 256, 0, stream>>>(x, xbf);
        k_cvt<<<H_ * I_ / 1024, 256, 0, stream>>>(wih, wihbf);
        k_xproj<<<S_, 256, 0, stream>>>(xbf, wihbf, bias, hid);
    } else {
        k_transpose<<<dim3(I_ / 32, H_ / 32), dim3(32, 8), 0, stream>>>(wih, wihT, H_, I_);
        k_xproj_f32<<<dim3(S_, H_ / 64), 256, 0, stream>>>(x, wihT, bias, hid);
    }

    unsigned short* hp[2] = {hbf0, hbf1};
    for (int t = 0; t < S_; ++t)
        k_step<<<64, 256, 0, stream>>>(whhbf, hp[t & 1], hp[(t + 1) & 1], hid, t);

    k_fc<<<B_, 256, 0, stream>>>(fcwT, fcb, hid, outp);
}

// Round 13
// 3490.695 us; speedup vs baseline: 2.0001x; 1.0321x over previous
//
#include <hip/hip_runtime.h>
#include <hip/hip_bf16.h>
#include <math.h>

#define B_ 64
#define S_ 512
#define I_ 256
#define H_ 1024
#define O_ 256

#define OUT_OFF (B_*O_)      // 16384 floats: final output
#define SLOT    (B_*H_)      // 65536 floats per hidden timestep slot

typedef __attribute__((ext_vector_type(8))) short bf16x8;  // 8 bf16 = 4 VGPRs
typedef __attribute__((ext_vector_type(4))) float f32x4;

#define LDSK 1032            // padded row stride (1024 + 8 bf16): 2-way bank alias only (free)

__device__ inline unsigned short bfb(float f) {
    return __builtin_bit_cast(unsigned short, __float2bfloat16(f));
}

// ---------------- zero hidden slot 0 (h0 = 0) + hbf0 ----------------
__global__ void k_zero(float* __restrict__ hid, float* __restrict__ hbf0) {
    int i = blockIdx.x * 256 + threadIdx.x;          // 64 blocks * 256 = 16384 float4
    ((float4*)hid)[i] = make_float4(0.f, 0.f, 0.f, 0.f);
    if (i < B_ * H_ * 2 / 16)                        // 8192 float4 = 128 KB bf16 zeros
        ((float4*)hbf0)[i] = make_float4(0.f, 0.f, 0.f, 0.f);
}

// ---------------- generic fp32 -> bf16 convert (count = grid*1024 elems) ----------------
__global__ void k_cvt(const float* __restrict__ src, unsigned short* __restrict__ dst) {
    int i = blockIdx.x * 256 + threadIdx.x;
    float4 v = ((const float4*)src)[i];
    ushort4 o;
    o.x = bfb(v.x); o.y = bfb(v.y); o.z = bfb(v.z); o.w = bfb(v.w);
    ((ushort4*)dst)[i] = o;
}

// ---------------- generic transpose src[R][C] -> dst[C][R] ----------------
__global__ void k_transpose(const float* __restrict__ src, float* __restrict__ dst,
                            int R, int C) {
    __shared__ float tile[32][33];
    int c0 = blockIdx.x * 32, r0 = blockIdx.y * 32;
    int tx = threadIdx.x, ty = threadIdx.y;          // block (32,8)
#pragma unroll
    for (int j = 0; j < 32; j += 8)
        tile[ty + j][tx] = src[(size_t)(r0 + ty + j) * C + c0 + tx];
    __syncthreads();
#pragma unroll
    for (int j = 0; j < 32; j += 8)
        dst[(size_t)(c0 + ty + j) * R + r0 + tx] = tile[tx][ty + j];
}

// ---------------- x_proj via MFMA (verified R4/R5/R12): hid[t+1][b][h] = bias + x.Wih ----------------
__global__ __launch_bounds__(256) void k_xproj(const unsigned short* __restrict__ xbf,   // [B][S][I]
                                               const unsigned short* __restrict__ wihbf, // [H][I]
                                               const float* __restrict__ bias,
                                               float* __restrict__ hid) {
    const int t    = blockIdx.x;
    const int lane = threadIdx.x & 63;
    const int w    = threadIdx.x >> 6;
    const int n    = lane & 15;
    const int quad = lane >> 4;

    bf16x8 afr[4][8];
#pragma unroll
    for (int bt = 0; bt < 4; ++bt) {
        const unsigned short* xp_ = xbf + ((size_t)(bt * 16 + n) * S_ + t) * I_ + quad * 8;
#pragma unroll
        for (int kk = 0; kk < 8; ++kk)
            afr[bt][kk] = *(const bf16x8*)(xp_ + kk * 32);
    }

    float* slot1 = hid + (size_t)(t + 1) * SLOT;
#pragma unroll 1
    for (int ht = 0; ht < 16; ++ht) {
        const int h0 = w * 256 + ht * 16;
        const unsigned short* wp = wihbf + (size_t)(h0 + n) * I_ + quad * 8;
        bf16x8 bfr[8];
#pragma unroll
        for (int kk = 0; kk < 8; ++kk) bfr[kk] = *(const bf16x8*)(wp + kk * 32);
        float bv = bias[h0 + n];
#pragma unroll
        for (int bt = 0; bt < 4; ++bt) {
            f32x4 acc = {0.f, 0.f, 0.f, 0.f};
#pragma unroll
            for (int kk = 0; kk < 8; ++kk)
                acc = __builtin_amdgcn_mfma_f32_16x16x32_bf16(afr[bt][kk], bfr[kk], acc, 0, 0, 0);
            const int b0 = bt * 16 + quad * 4;
#pragma unroll
            for (int r = 0; r < 4; ++r)
                slot1[(size_t)(b0 + r) * H_ + h0 + n] = acc[r] + bv;
        }
    }
}

// ---------------- fp32 fallback x_proj (small workspace; baseline-verified) ----------------
__global__ __launch_bounds__(256) void k_xproj_f32(const float* __restrict__ x,
                                                   const float* __restrict__ wihT, // [I_][H_]
                                                   const float* __restrict__ bias,
                                                   float* __restrict__ hid) {
    const int t   = blockIdx.x;
    const int hq0 = blockIdx.y * 16;
    __shared__ float xs[B_][260];
    const int tid = threadIdx.x;
#pragma unroll
    for (int it = 0; it < 16; ++it) {
        int f4 = it * 256 + tid;
        int b = f4 >> 6, iq = f4 & 63;
        float4 v = ((const float4*)x)[(size_t)b * (S_ * I_ / 4) + t * (I_ / 4) + iq];
        *(float4*)&xs[b][iq * 4] = v;
    }
    __syncthreads();
    const int hq = tid & 15;
    const int b0 = (tid >> 4) * 4;
    float4 acc[4];
    float4 bs = ((const float4*)bias)[hq0 + hq];
#pragma unroll
    for (int i = 0; i < 4; ++i) acc[i] = bs;
    const float4* w4p = (const float4*)wihT;
#pragma unroll 4
    for (int k = 0; k < I_; ++k) {
        float4 w = w4p[(size_t)k * (H_ / 4) + hq0 + hq];
#pragma unroll
        for (int i = 0; i < 4; ++i) {
            float xv = xs[b0 + i][k];
            acc[i].x += xv * w.x; acc[i].y += xv * w.y;
            acc[i].z += xv * w.z; acc[i].w += xv * w.w;
        }
    }
    float4* out4 = (float4*)hid;
#pragma unroll
    for (int i = 0; i < 4; ++i)
        out4[(size_t)(t + 1) * (SLOT / 4) + (b0 + i) * (H_ / 4) + hq0 + hq] = acc[i];
}

// ---------------- one recurrence step (R12-verified mapping + issue-order optimization) ----------------
// D[16r x 16b] = W_rows[16 x 1024] * hT[1024 x 16b]; A = whhbf rows (LDS), B = hprev (registers).
// grid 64 (slice = 16 r-rows), 256 thr = 4 waves, wave w = b-tile.
// All long-latency loads (W-stage, 32 h-fragments, xp) issue BEFORE the LDS writes +
// barrier, so remote-L2/L3 h latency hides under staging instead of serializing after it.
__global__ __launch_bounds__(256, 1) void k_step(
    const unsigned short* __restrict__ whhbf,   // [H_][H_] bf16 natural
    const unsigned short* __restrict__ hprev,   // [B_][H_] bf16
    unsigned short* __restrict__ hnext,         // [B_][H_] bf16
    float* __restrict__ hid, int t)
{
    const int slice = blockIdx.x;
    __shared__ unsigned short Ws[16 * LDSK];
    const int tid = threadIdx.x;

    const int w    = tid >> 6;                       // wave = b-tile
    const int lane = tid & 63;
    const int n    = lane & 15;                      // A-row (r_local) AND B-col (b_local)
    const int quad = lane >> 4;
    const int b    = w * 16 + n;

    // 1) W staging loads (L2-hot; needed first, return first)
    const float4* src = (const float4*)(whhbf + (size_t)slice * 16 * H_);
    float4 wst[8];
#pragma unroll
    for (int it = 0; it < 8; ++it)
        wst[it] = src[it * 256 + tid];

    // 2) ALL 32 h-fragment loads (remote-L2/L3, ~600-900 cyc) — stay outstanding
    //    through the staging writes + barrier; consumed from registers by MFMA.
    const unsigned short* bp = hprev + (size_t)b * H_ + quad * 8;
    bf16x8 hfr[32];                                  // 128 VGPRs, statically indexed
#pragma unroll
    for (int kk = 0; kk < 32; ++kk)
        hfr[kk] = *(const bf16x8*)(bp + kk * 32);

    // 3) xp prefetch (needed only in the epilogue)
    const int r0 = slice * 16 + quad * 4;
    float4* slot1 = (float4*)(hid + (size_t)(t + 1) * SLOT);
    const size_t idx = (size_t)b * (H_ / 4) + (r0 >> 2);
    float4 xp = slot1[idx];

    // 4) LDS writes (wait only on the 8 W loads), then barrier
#pragma unroll
    for (int it = 0; it < 8; ++it) {
        int c = it * 256 + tid;                      // 2048 chunks of 16B (8 bf16)
        int row = c >> 7, off = (c & 127) * 8;
        *(float4*)&Ws[row * LDSK + off] = wst[it];
    }
    __syncthreads();

    // 5) MFMA: A-fragments from LDS, B-fragments from prefetched registers
    const unsigned short* ap = &Ws[n * LDSK + quad * 8];
    f32x4 acc0 = {0.f, 0.f, 0.f, 0.f};
    f32x4 acc1 = {0.f, 0.f, 0.f, 0.f};               // 2 chains: halve dependent MFMA latency
#pragma unroll
    for (int kk = 0; kk < 32; kk += 2) {
        bf16x8 a0 = *(const bf16x8*)(ap + kk * 32);
        acc0 = __builtin_amdgcn_mfma_f32_16x16x32_bf16(a0, hfr[kk], acc0, 0, 0, 0);
        bf16x8 a1 = *(const bf16x8*)(ap + (kk + 1) * 32);
        acc1 = __builtin_amdgcn_mfma_f32_16x16x32_bf16(a1, hfr[kk + 1], acc1, 0, 0, 0);
    }

    // C/D: row(M=r_local) = quad*4 + reg, col(N=b_local) = lane&15
    float4 hv;
    hv.x = tanhf(acc0[0] + acc1[0] + xp.x);
    hv.y = tanhf(acc0[1] + acc1[1] + xp.y);
    hv.z = tanhf(acc0[2] + acc1[2] + xp.z);
    hv.w = tanhf(acc0[3] + acc1[3] + xp.w);
    slot1[idx] = hv;

    ushort4 hb;
    hb.x = bfb(hv.x);
    hb.y = bfb(hv.y);
    hb.z = bfb(hv.z);
    hb.w = bfb(hv.w);
    *(ushort4*)(hnext + (size_t)b * H_ + r0) = hb;
}

// ---------------- final fc (baseline-verified) ----------------
__global__ __launch_bounds__(256) void k_fc(const float* __restrict__ fcwT,  // [H_][O_]
                                            const float* __restrict__ fcb,
                                            const float* __restrict__ hid,
                                            float* __restrict__ outp) {
    const int b = blockIdx.x;
    __shared__ float hl[H_];
    const int tid = threadIdx.x;
    ((float4*)hl)[tid] = ((const float4*)(hid + (size_t)S_ * SLOT + b * H_))[tid];
    __syncthreads();
    float acc = fcb[tid];
#pragma unroll 4
    for (int k = 0; k < H_; ++k)
        acc += fcwT[(size_t)k * O_ + tid] * hl[k];
    outp[b * O_ + tid] = acc;
}

extern "C" void kernel_launch(void* const* d_in, const int* in_sizes, int n_in,
                              void* d_out, int out_size, void* d_ws, size_t ws_size,
                              hipStream_t stream) {
    const float* x    = (const float*)d_in[0];
    const float* wih  = (const float*)d_in[1];
    const float* whh  = (const float*)d_in[2];
    const float* bias = (const float*)d_in[3];
    const float* fcw  = (const float*)d_in[4];
    const float* fcb  = (const float*)d_in[5];

    float* outp = (float*)d_out;
    float* hid  = outp + OUT_OFF;

    // big:   whhbf 2M | xbf 16.8M | wihbf 0.5M | fcwT 1M | hbf0 128K | hbf1 128K
    // small: whhbf 2M | wihT 1M | fcwT 1M | hbf0 128K | hbf1 128K   (~4.3MB)
    unsigned short* whhbf = (unsigned short*)d_ws;
    const size_t need_big = (size_t)H_ * H_ * 2 + (size_t)B_ * S_ * I_ * 2 +
                            (size_t)H_ * I_ * 2 + (size_t)H_ * O_ * 4 +
                            (size_t)B_ * H_ * 4 + 1024;
    const bool big = ws_size >= need_big;

    unsigned short* xbf   = whhbf + (size_t)H_ * H_;
    unsigned short* wihbf = xbf + (size_t)B_ * S_ * I_;
    float* fcwT_big = (float*)(wihbf + (size_t)H_ * I_);
    unsigned short* hb0_big = (unsigned short*)(fcwT_big + (size_t)H_ * O_);

    float* wihT = (float*)(whhbf + (size_t)H_ * H_);
    float* fcwT_sm = wihT + (size_t)I_ * H_;
    unsigned short* hb0_sm = (unsigned short*)(fcwT_sm + (size_t)H_ * O_);

    float* fcwT = big ? fcwT_big : fcwT_sm;
    unsigned short* hbf0 = big ? hb0_big : hb0_sm;
    unsigned short* hbf1 = hbf0 + (size_t)B_ * H_;

    k_zero<<<SLOT / 4 / 256, 256, 0, stream>>>(hid, (float*)hbf0);
    k_cvt<<<H_ * H_ / 1024, 256, 0, stream>>>(whh, whhbf);
    k_transpose<<<dim3(H_ / 32, O_ / 32), dim3(32, 8), 0, stream>>>(fcw, fcwT, O_, H_);

    if (big) {
        k_cvt<<<B_ * S_ * I_ / 1024, 256, 0, stream>>>(x, xbf);
        k_cvt<<<H_ * I_ / 1024, 256, 0, stream>>>(wih, wihbf);
        k_xproj<<<S_, 256, 0, stream>>>(xbf, wihbf, bias, hid);
    } else {
        k_transpose<<<dim3(I_ / 32, H_ / 32), dim3(32, 8), 0, stream>>>(wih, wihT, H_, I_);
        k_xproj_f32<<<dim3(S_, H_ / 64), 256, 0, stream>>>(x, wihT, bias, hid);
    }

    unsigned short* hp[2] = {hbf0, hbf1};
    for (int t = 0; t < S_; ++t)
        k_step<<<64, 256, 0, stream>>>(whhbf, hp[t & 1], hp[(t + 1) & 1], hid, t);

    k_fc<<<B_, 256, 0, stream>>>(fcwT, fcb, hid, outp);
}